// Round 4
// baseline (252466.064 us; speedup 1.0000x reference)
//
#include <hip/hip_runtime.h>

#define S_LEN 32768
#define EMB   256
#define HID   512
#define G3H   1536   // 3*HID
#define NBLK  128    // launched; active iff bid%8==0 (co-locate on one XCD)
#define NACT  16     // active blocks
#define NTHR  512
#define NOUT  8

// ws layout (float units):
// [0, 9216)        gx_table (6 x 1536)  : emb@W_ih.T + b_ih
// [9216, 11264)    hbuf: 2 x 512 tagged u64 words. word = (tag<<32)|f32bits
#define WS_GX    0
#define WS_HBUF  9216

__global__ __launch_bounds__(256) void gru_precompute_kernel(
    const float* __restrict__ emb, const float* __restrict__ W_ih,
    const float* __restrict__ b_ih, float* __restrict__ ws)
{
    int idx = blockIdx.x * 256 + threadIdx.x;
    if (idx < 6 * G3H) {
        int v = idx / G3H, r = idx - v * G3H;
        const float* er = emb + v * EMB;
        const float* wr = W_ih + r * EMB;
        float s = 0.f;
        #pragma unroll 8
        for (int e = 0; e < EMB; ++e) s += er[e] * wr[e];
        ws[WS_GX + idx] = s + b_ih[r];
    }
}

// Persistent GRU: 16 active WGs x 512 thr. WG rank r owns h rows [r*32,r*32+32).
// Thread mapping: rowg = tid>>4 (one of 32 rows), k = tid&15 owns columns
// [k*32, k*32+32) for ALL 3 gates = 24 float4 = 96 weight VGPRs/lane.
// Column chunks are processed in k-rotated order so the 16 lanes' ds_read_b128
// spread across bank-quads (2-way max = free).
// h exchange: tagged (tag<<32|value) u64 words. Producer double-stores
// (sc0 -> shared XCD L2 fast path; sc0 sc1 -> MALL safety). Consumer polls
// sc0, escalating to sc0 sc1 every 64 misses. Tag exact-match + back-pressure
// make any mix of stale reads safe (never falsely consumed, never deadlocks).
__global__ __launch_bounds__(512, 2) void gru_persistent_kernel(
    const int* __restrict__ seq, const float* __restrict__ W_hh,
    const float* __restrict__ b_hh, const float* __restrict__ W_out,
    const float* __restrict__ b_out, float* __restrict__ ws,
    float* __restrict__ out)
{
    if (blockIdx.x & 7) return;                 // keep one block per CU on XCD0
    const int r    = blockIdx.x >> 3;           // rank 0..15
    const int tid  = threadIdx.x;
    const int k    = tid & 15;                  // column-slice lane
    const int rowg = tid >> 4;                  // local row 0..31
    const int row  = r * 32 + rowg;             // global h row

    __shared__ __align__(16) float h_lds[2][HID];
    __shared__ float gx_lds[6 * 96];            // [v][gate][rowg], b_hh folded for r,z
    __shared__ float bhn_lds[32];
    __shared__ unsigned char seq_lds[S_LEN];

    unsigned long long* hbuf = (unsigned long long*)(ws + WS_HBUF);

    // ---- one-time weight load into registers (k-rotated chunk order) ----
    float4 WR[8], WZ[8], WN[8];
    {
        const float4* pr = (const float4*)(W_hh + (size_t)(0 * HID + row) * HID + k * 32);
        const float4* pz = (const float4*)(W_hh + (size_t)(1 * HID + row) * HID + k * 32);
        const float4* pn = (const float4*)(W_hh + (size_t)(2 * HID + row) * HID + k * 32);
        #pragma unroll
        for (int c = 0; c < 8; ++c) {
            int cc = (c + k) & 7;
            WR[c] = pr[cc]; WZ[c] = pz[cc]; WN[c] = pn[cc];
        }
    }

    // ---- one-time LDS staging ----
    for (int idx = tid; idx < 6 * 96; idx += NTHR) {
        int v = idx / 96, rem = idx - v * 96, gate = rem >> 5, j = rem & 31;
        float val = ws[WS_GX + v * G3H + gate * HID + r * 32 + j];
        if (gate < 2) val += b_hh[gate * HID + r * 32 + j];
        gx_lds[idx] = val;
    }
    if (tid < 32) bhn_lds[tid] = b_hh[2 * HID + r * 32 + tid];
    for (int q = tid; q < S_LEN; q += NTHR) seq_lds[q] = (unsigned char)seq[q];

    // ---- zero-init OWN hbuf words, both parities (kills stale tags from
    // prior graph replays; own-L2 + MALL copies both refreshed) ----
    if (tid < 64) {
        unsigned long long* dst = &hbuf[(tid >> 5) * HID + r * 32 + (tid & 31)];
        unsigned long long zero = 0ull;
        asm volatile("global_store_dwordx2 %0, %1, off sc0\n\t"
                     "global_store_dwordx2 %0, %1, off sc0 sc1"
                     :: "v"(dst), "v"(zero) : "memory");
    }
    __syncthreads();   // drains vmcnt: zero-init ordered before t-loop stores

    for (int t = 0; t < S_LEN; ++t) {
        const int p = t & 1;
        int v = seq_lds[t];
        float gxr = gx_lds[v * 96 + rowg];
        float gxz = gx_lds[v * 96 + 32 + rowg];
        float gxn = gx_lds[v * 96 + 64 + rowg];

        // poll own tagged word (sc0 fast path, periodic MALL escalation)
        {
            const unsigned long long* src = &hbuf[p * HID + tid];
            unsigned long long w;
            int spin = 0;
            for (;;) {
                if ((++spin & 63) == 0)
                    asm volatile("global_load_dwordx2 %0, %1, off sc0 sc1\n\t"
                                 "s_waitcnt vmcnt(0)"
                                 : "=v"(w) : "v"(src) : "memory");
                else
                    asm volatile("global_load_dwordx2 %0, %1, off sc0\n\t"
                                 "s_waitcnt vmcnt(0)"
                                 : "=v"(w) : "v"(src) : "memory");
                if ((unsigned)(w >> 32) == (unsigned)t) break;
            }
            h_lds[p][tid] = __uint_as_float((unsigned)w);
        }
        __syncthreads();   // sole barrier per step (parity double buffer)

        // dot over this lane's 32 columns (rotated chunk order matches weights)
        float ar = 0.f, az = 0.f, an = 0.f;
        const float4* hp = (const float4*)&h_lds[p][k * 32];
        #pragma unroll
        for (int c = 0; c < 8; ++c) {
            float4 hv = hp[(c + k) & 7];
            ar += WR[c].x * hv.x; ar += WR[c].y * hv.y;
            ar += WR[c].z * hv.z; ar += WR[c].w * hv.w;
            az += WZ[c].x * hv.x; az += WZ[c].y * hv.y;
            az += WZ[c].z * hv.z; az += WZ[c].w * hv.w;
            an += WN[c].x * hv.x; an += WN[c].y * hv.y;
            an += WN[c].z * hv.z; an += WN[c].w * hv.w;
        }
        // reduce across the 16 lanes of the column group
        #pragma unroll
        for (int m = 1; m < 16; m <<= 1) {
            ar += __shfl_xor(ar, m, 16);
            az += __shfl_xor(az, m, 16);
            an += __shfl_xor(an, m, 16);
        }

        float rg = __fdividef(1.f, 1.f + __expf(-(gxr + ar)));
        float zg = __fdividef(1.f, 1.f + __expf(-(gxz + az)));
        float nx = gxn + rg * (an + bhn_lds[rowg]);
        float ng = 1.f - __fdividef(2.f, 1.f + __expf(2.f * nx));  // tanh
        float hold = h_lds[p][row];
        float hn = (1.f - zg) * ng + zg * hold;

        if (k == 0) {
            unsigned long long wout =
                ((unsigned long long)(unsigned)(t + 1) << 32) |
                (unsigned long long)__float_as_uint(hn);
            unsigned long long* dst = &hbuf[(1 - p) * HID + row];
            asm volatile("global_store_dwordx2 %0, %1, off sc0\n\t"
                         "global_store_dwordx2 %0, %1, off sc0 sc1"
                         :: "v"(dst), "v"(wout) : "memory");
        }
        // no trailing barrier: next step stages into h_lds[1-p]
    }

    // ---- epilogue: rank-0 WG computes out = W_out @ h_T + b_out ----
    if (r == 0) {
        // h_{S_LEN} lives in parity 0 with tag S_LEN
        const unsigned long long* src = &hbuf[0 * HID + tid];
        unsigned long long w;
        int spin = 0;
        for (;;) {
            if ((++spin & 63) == 0)
                asm volatile("global_load_dwordx2 %0, %1, off sc0 sc1\n\t"
                             "s_waitcnt vmcnt(0)"
                             : "=v"(w) : "v"(src) : "memory");
            else
                asm volatile("global_load_dwordx2 %0, %1, off sc0\n\t"
                             "s_waitcnt vmcnt(0)"
                             : "=v"(w) : "v"(src) : "memory");
            if ((unsigned)(w >> 32) == (unsigned)S_LEN) break;
        }
        h_lds[0][tid] = __uint_as_float((unsigned)w);
        __syncthreads();
        // wave wid computes out[wid] (NOUT == 8 == waves per WG)
        const int wid  = tid >> 6;
        const int lane = tid & 63;
        float s = 0.f;
        #pragma unroll
        for (int m = 0; m < 8; ++m) {
            int j = lane + 64 * m;
            s += W_out[wid * HID + j] * h_lds[0][j];
        }
        #pragma unroll
        for (int m = 1; m < 64; m <<= 1) s += __shfl_xor(s, m, 64);
        if (lane == 0) out[wid] = s + b_out[wid];
    }
}

extern "C" void kernel_launch(void* const* d_in, const int* in_sizes, int n_in,
                              void* d_out, int out_size, void* d_ws, size_t ws_size,
                              hipStream_t stream) {
    const int*   seq   = (const int*)d_in[0];
    const float* emb   = (const float*)d_in[1];
    const float* W_ih  = (const float*)d_in[2];
    const float* W_hh  = (const float*)d_in[3];
    const float* b_ih  = (const float*)d_in[4];
    const float* b_hh  = (const float*)d_in[5];
    const float* W_out = (const float*)d_in[6];
    const float* b_out = (const float*)d_in[7];
    float* ws = (float*)d_ws;
    float* out = (float*)d_out;

    gru_precompute_kernel<<<36, 256, 0, stream>>>(emb, W_ih, b_ih, ws);
    gru_persistent_kernel<<<NBLK, NTHR, 0, stream>>>(seq, W_hh, b_hh, W_out, b_out,
                                                     ws, out);
}